// Round 8
// baseline (168.994 us; speedup 1.0000x reference)
//
#include <hip/hip_runtime.h>
#include <hip/hip_fp16.h>

// GAT (2 heads x 64) + PReLU, N=50000, E=800000, feat 128.
// R18: scale out the binning phases (kB/kD machine coverage); k6/k1/k0 frozen.
//  - kB: CHUNK 2048 / NBLK 392 -> 392 blocks (full 256-CU coverage, 2x the
//    waves/CU of the old 196-block launch). CCAP 40 = mean 10.45 + 9.1 sigma.
//  - kD: 2 blocks per bucket (drel bit 7 split, proven in R12's k5): 392x512
//    -> ~12 waves/CU, half the per-block LDS-atomic serial chain. Costs a 2x
//    coarse re-read (~+13 MB), bought back by halved latency exposure.
//  - k6_pass identical to R17 (8 nodes x 8 lanes x half4, slice-major xs,
//    pass->XCD pinning). k0/k1 identical.

#define N_NODES 50000
#define N_EDGES 800000
#define CAP     56        // max in-degree; deg ~ Poisson(16), P(>56) ~ 1e-9
#define BSH     8         // bucket shift: 256 nodes per bucket
#define NB      196       // ceil(N / 256) buckets
#define CHUNK   2048      // edges per kB block
#define NBLK    392       // ceil(E / CHUNK)
#define CCAP    40        // slots per (bucket,chunk) cell; mean 10.45, 9.1 sigma
#define HALFP   20        // pair-slots per cell

// d_ws layout (bytes); total 36,237,120 (R10 proven footprint)
#define OFF_A      0          // a_all: N*4 floats          =   800000
#define OFF_CNT    800000     // cnt:   N ints              =   200000
#define OFF_XS     1000256    // xs:    4*N*32 halves       = 12800000
#define OFF_BKT    13800256   // bkt:   N*CAP int2          = 22400000 (ends 36,200,256)
#define OFF_SWZ    36200256   // swizzled B: 2304 * 16 B    =    36864
// d_out scratch (dead before k6_pass overwrites all 25.6 MB):
#define DOUT_COARSE 0         // NB*NBLK*CCAP*8 = 196*392*40*8 = 24,586,240
#define DOUT_CELL   24586240  // cellcnt = NB*NBLK*4 = 307,328
                              // total 24,893,568 < 25,600,000 (d_out)

typedef _Float16 f16x8 __attribute__((ext_vector_type(8)));
typedef _Float16 f16x4 __attribute__((ext_vector_type(4)));
typedef float    f32x4 __attribute__((ext_vector_type(4)));
typedef int      i32x4 __attribute__((ext_vector_type(4)));
typedef unsigned long long u64;

// ---------------------------------------------------------------------------
// k0_prep: build B-fragment buffer for GEMM x @ [W_src | V].
__global__ __launch_bounds__(256) void k0_prep(
    const float* __restrict__ Wsrc, const float* __restrict__ Wdst,
    const float* __restrict__ att_s, const float* __restrict__ att_d,
    __half* __restrict__ swz)
{
    __shared__ float vS[128 * 4];
    const int nt = blockIdx.x;
    const int t = threadIdx.x;
    if (nt == 8) {
        if (t < 128) {
            const float* wsp = Wsrc + t * 128;
            const float* wdp = Wdst + t * 128;
            float a0 = 0.f, a1 = 0.f, a2 = 0.f, a3 = 0.f;
#pragma unroll 8
            for (int c = 0; c < 64; ++c) {
                a0 += wsp[c]      * att_s[c];
                a1 += wsp[64 + c] * att_s[64 + c];
                a2 += wdp[c]      * att_d[c];
                a3 += wdp[64 + c] * att_d[64 + c];
            }
            *(float4*)(vS + t * 4) = make_float4(a0, a1, a2, a3);
        }
        __syncthreads();
    }
    const int kb = t >> 6, L = t & 63;
    const int col = L & 15;
    const int krow = kb * 32 + ((L >> 4) & 3) * 8;
    f16x8 v;
    if (nt < 8) {
#pragma unroll
        for (int j = 0; j < 8; ++j)
            v[j] = (_Float16)Wsrc[(size_t)(krow + j) * 128 + nt * 16 + col];
    } else {
#pragma unroll
        for (int j = 0; j < 8; ++j)
            v[j] = (col < 4) ? (_Float16)vS[(krow + j) * 4 + col] : (_Float16)0.f;
    }
    *(f16x8*)(swz + ((size_t)(kb * 9 + nt) * 64 + L) * 8) = v;
}

// ---------------------------------------------------------------------------
// k1: MFMA GEMM x @ [W_src | V]. Block = 4 waves; wave: 16 rows x 144 cols, K=128.
// Epilogue writes xs in slice-major layout [4][N][32].
__global__ __launch_bounds__(256) void k1_gemm(
    const float* __restrict__ x, const __half* __restrict__ swz,
    __half* __restrict__ xs, float* __restrict__ a_all)
{
    __shared__ __half tile[64 * 136];   // row stride 272B (16B-mult); 17.4 KB
    const int t = threadIdx.x;
    const int w = t >> 6, L = t & 63;
    const int m = L & 15, q = L >> 4;
    const int n_a = blockIdx.x * 64 + w * 16 + m;
    const int rrow = (n_a < N_NODES) ? n_a : (N_NODES - 1);
    const float* xrow = x + (size_t)rrow * 128;

    f32x4 acc[9];
#pragma unroll
    for (int nt = 0; nt < 9; ++nt) acc[nt] = (f32x4){0.f, 0.f, 0.f, 0.f};

#pragma unroll
    for (int kb = 0; kb < 4; ++kb) {
        const int k0 = kb * 32 + q * 8;
        float4 xa = *(const float4*)(xrow + k0);
        float4 xb = *(const float4*)(xrow + k0 + 4);
        f16x8 a;
        a[0] = (_Float16)xa.x; a[1] = (_Float16)xa.y;
        a[2] = (_Float16)xa.z; a[3] = (_Float16)xa.w;
        a[4] = (_Float16)xb.x; a[5] = (_Float16)xb.y;
        a[6] = (_Float16)xb.z; a[7] = (_Float16)xb.w;
        const f16x8* bbase = (const f16x8*)swz + (size_t)(kb * 9) * 64 + L;
#pragma unroll
        for (int nt = 0; nt < 9; ++nt) {
            f16x8 b = bbase[(size_t)nt * 64];
            acc[nt] = __builtin_amdgcn_mfma_f32_16x16x32_f16(a, b, acc[nt], 0, 0, 0);
        }
    }

    // xs epilogue: C/D layout col = lane&15, row = (lane>>4)*4 + reg
    const int rloc = w * 16 + q * 4;              // row-in-tile base for this lane
#pragma unroll
    for (int nt = 0; nt < 8; ++nt) {
#pragma unroll
        for (int r = 0; r < 4; ++r)
            tile[(rloc + r) * 136 + nt * 16 + m] = (__half)acc[nt][r];
    }
    __syncthreads();
    const int n0 = blockIdx.x * 64;
#pragma unroll
    for (int cc = 0; cc < 4; ++cc) {
        int task = cc * 256 + t;                  // 1024 tasks = 64 rows x 16 chunks
        int row = task >> 4, ch = task & 15;      // chunk = 8 halves (cols ch*8..+7)
        int n = n0 + row;
        if (n < N_NODES) {
            ulonglong2 v = *(const ulonglong2*)(tile + row * 136 + ch * 8);
            // slice-major: slice p = ch>>2, in-slice offset (ch&3)*8 halves
            *(ulonglong2*)(xs + ((size_t)(ch >> 2) * N_NODES + n) * 32 + (ch & 3) * 8) = v;
        }
    }

    // a_all from tile 8 (fp32, 4 cols)
    if (m < 4) {
#pragma unroll
        for (int r = 0; r < 4; ++r) {
            int n = n0 + rloc + r;
            if (n < N_NODES) a_all[(size_t)n * 4 + m] = acc[8][r];
        }
    }
}

// ---------------------------------------------------------------------------
// kB: per-chunk scatter into this chunk's private cells. CHUNK 2048 -> 392
// blocks for full-chip coverage; logic identical to the proven R11 kernel.
__global__ __launch_bounds__(256) void kB_bin(
    const int* __restrict__ ei, const float* __restrict__ a_all,
    u64* __restrict__ coarse, int* __restrict__ cellcnt)
{
    __shared__ int lcnt[NB];
    const int t = threadIdx.x;
    if (t < NB) lcnt[t] = 0;
    __syncthreads();
    const int e0 = blockIdx.x * CHUNK;
#pragma unroll
    for (int u = 0; u < 4; ++u) {
        int e = e0 + u * 512 + t * 2;             // even; E even -> e+1 valid too
        if (e < N_EDGES) {
            int2 ss = *(const int2*)(ei + e);
            int2 dd = *(const int2*)(ei + N_EDGES + e);
            float2 as0 = *(const float2*)(a_all + (size_t)ss.x * 4);
            float2 ad0 = *(const float2*)(a_all + (size_t)dd.x * 4 + 2);
            float2 as1 = *(const float2*)(a_all + (size_t)ss.y * 4);
            float2 ad1 = *(const float2*)(a_all + (size_t)dd.y * 4 + 2);
            float e00 = as0.x + ad0.x, e01 = as0.y + ad0.y;
            float e10 = as1.x + ad1.x, e11 = as1.y + ad1.y;
            e00 = (e00 >= 0.f) ? e00 : 0.2f * e00;
            e01 = (e01 >= 0.f) ? e01 : 0.2f * e01;
            e10 = (e10 >= 0.f) ? e10 : 0.2f * e10;
            e11 = (e11 >= 0.f) ? e11 : 0.2f * e11;
            // no max-shift: |e| small -> exp safe in fp32, math identical
            __half2 hw0 = __floats2half2_rn(__expf(e00), __expf(e01));
            __half2 hw1 = __floats2half2_rn(__expf(e10), __expf(e11));
            unsigned lo0 = (unsigned)ss.x | ((unsigned)(dd.x & 255) << 16);
            unsigned lo1 = (unsigned)ss.y | ((unsigned)(dd.y & 255) << 16);
            u64 ent0 = (u64)lo0 | ((u64)*reinterpret_cast<unsigned*>(&hw0) << 32);
            u64 ent1 = (u64)lo1 | ((u64)*reinterpret_cast<unsigned*>(&hw1) << 32);
            int b0 = dd.x >> BSH, b1 = dd.y >> BSH;
            int p0 = atomicAdd(&lcnt[b0], 1);
            int p1 = atomicAdd(&lcnt[b1], 1);
            if (p0 < CCAP)
                coarse[((size_t)b0 * NBLK + blockIdx.x) * CCAP + p0] = ent0;
            if (p1 < CCAP)
                coarse[((size_t)b1 * NBLK + blockIdx.x) * CCAP + p1] = ent1;
        }
    }
    __syncthreads();
    if (t < NB) {
        int c = lcnt[t];
        cellcnt[t * NBLK + blockIdx.x] = (c < CCAP) ? c : CCAP;
    }
}

// ---------------------------------------------------------------------------
// kD: TWO 512-thread blocks per 256-node bucket (drel bit 7 split, as in
// R12's k5); per-dst cursors in LDS; gap-skipping slot-pair (16B) reads;
// zero-pads each bkt row to a multiple of 8 entries (src=0,w=0 inert).
__global__ __launch_bounds__(512) void kD_fine(
    const u64* __restrict__ coarse, const int* __restrict__ cellcnt,
    int* __restrict__ cnt, int2* __restrict__ bkt)
{
    __shared__ int cur[128];
    __shared__ int ccnt[NBLK];
    const int b = blockIdx.x >> 1, t = threadIdx.x;
    const int hi = (blockIdx.x & 1) << 7;            // which 128-node half we own
    if (t < 128) cur[t] = 0;
    if (t < NBLK) ccnt[t] = cellcnt[b * NBLK + t];
    __syncthreads();
    const u64* src = coarse + (size_t)b * NBLK * CCAP;
    for (int g2 = t; g2 < NBLK * HALFP; g2 += 512) {
        int c = g2 / HALFP, sp = (g2 - c * HALFP) * 2;
        int cc = ccnt[c];
        if (sp < cc) {
            ulonglong2 pr = *(const ulonglong2*)(src + (size_t)c * CCAP + sp);
            {
                unsigned lo = (unsigned)pr.x;
                int drel = (lo >> 16) & 255;
                if ((drel & 128) == hi) {
                    int pos = atomicAdd(&cur[drel & 127], 1);
                    if (pos < CAP) {
                        int d = (b << BSH) + drel;
                        bkt[(size_t)d * CAP + pos] =
                            make_int2((int)(lo & 0xFFFF), (int)(unsigned)(pr.x >> 32));
                    }
                }
            }
            if (sp + 1 < cc) {
                unsigned lo = (unsigned)pr.y;
                int drel = (lo >> 16) & 255;
                if ((drel & 128) == hi) {
                    int pos = atomicAdd(&cur[drel & 127], 1);
                    if (pos < CAP) {
                        int d = (b << BSH) + drel;
                        bkt[(size_t)d * CAP + pos] =
                            make_int2((int)(lo & 0xFFFF), (int)(unsigned)(pr.y >> 32));
                    }
                }
            }
        }
    }
    __syncthreads();
    if (t < 128) {
        int d = (b << BSH) + hi + t;
        if (d < N_NODES) {
            int c = cur[t];
            cnt[d] = c;
            int cc = (c < CAP) ? c : CAP;
            int ce = (cc + 7) & ~7;                // pad to multiple of 8
            int2* r = bkt + (size_t)d * CAP;
            for (int p = cc; p < ce; ++p) r[p] = make_int2(0, 0);
        }
    }
}

// ---------------------------------------------------------------------------
// k6_pass: column-pass aggregation over slice-major xs; pass = blockIdx&3
// (HW round-robin -> XCD x sees pass x&3 only; slice 3.2 MB L2-resident).
// Wave = 8 nodes x 8 lanes x half4. (Identical to R17.)
__global__ __launch_bounds__(256) void k6_pass(
    const int2* __restrict__ bkt, const int* __restrict__ cnt,
    const __half* __restrict__ xs, const float* __restrict__ bias,
    const float* __restrict__ prelu_w, float* __restrict__ out)
{
    const int pass = blockIdx.x & 3;            // XCD (blockIdx%8) sees pass x&3 only
    const int grp  = blockIdx.x >> 2;           // 32 nodes per block
    const int t = threadIdx.x;
    const int w = t >> 6, lane = t & 63;
    const int l8 = lane & 7;                    // lane-in-node-group
    const int node = grp * 32 + w * 8 + (lane >> 3);
    const int c4 = l8 * 4;                      // in-slice column (4 cols/lane)
    const int j = pass * 32 + c4;               // global output column
    const int sh = (pass & 2) ? 16 : 0;         // head = col>=64
    const __half* xsp = xs + pass * (N_NODES * 32);   // 32-bit offset (6.4M)

    const bool valid = (node < N_NODES);
    int m = 0;
    if (valid) { m = cnt[node]; if (m > CAP) m = CAP; }
    const int mr = (m + 7) & ~7;                // padded-valid region
    const i32x4* row = (const i32x4*)(bkt + (valid ? node : 0) * CAP);

    float a0c = 0.f, a1c = 0.f, a2c = 0.f, a3c = 0.f, sw = 0.f;
    if (mr) {
        i32x4 e0 = row[0], e1 = row[1], e2 = row[2], e3 = row[3];
        int k = 0;
        for (;;) {
            const bool more = (k + 8 < mr);
            i32x4 f0, f1, f2, f3;
            if (more) {
                const i32x4* nr = row + ((k + 8) >> 1);
                f0 = nr[0]; f1 = nr[1]; f2 = nr[2]; f3 = nr[3];
            }
            // 8 xs loads (half4 = 8B each; 8 lanes cover the 64B slice row)
            f16x4 h0 = *(const f16x4*)(xsp + e0[0] * 32 + c4);
            f16x4 h1 = *(const f16x4*)(xsp + e0[2] * 32 + c4);
            f16x4 h2 = *(const f16x4*)(xsp + e1[0] * 32 + c4);
            f16x4 h3 = *(const f16x4*)(xsp + e1[2] * 32 + c4);
            f16x4 h4 = *(const f16x4*)(xsp + e2[0] * 32 + c4);
            f16x4 h5 = *(const f16x4*)(xsp + e2[2] * 32 + c4);
            f16x4 h6 = *(const f16x4*)(xsp + e3[0] * 32 + c4);
            f16x4 h7 = *(const f16x4*)(xsp + e3[2] * 32 + c4);
            float a0 = __half2float(__ushort_as_half((unsigned short)(((unsigned)e0[1]) >> sh)));
            float a1 = __half2float(__ushort_as_half((unsigned short)(((unsigned)e0[3]) >> sh)));
            float a2 = __half2float(__ushort_as_half((unsigned short)(((unsigned)e1[1]) >> sh)));
            float a3 = __half2float(__ushort_as_half((unsigned short)(((unsigned)e1[3]) >> sh)));
            float a4 = __half2float(__ushort_as_half((unsigned short)(((unsigned)e2[1]) >> sh)));
            float a5 = __half2float(__ushort_as_half((unsigned short)(((unsigned)e2[3]) >> sh)));
            float a6 = __half2float(__ushort_as_half((unsigned short)(((unsigned)e3[1]) >> sh)));
            float a7 = __half2float(__ushort_as_half((unsigned short)(((unsigned)e3[3]) >> sh)));
            a0c += (float)h0[0] * a0; a1c += (float)h0[1] * a0;
            a2c += (float)h0[2] * a0; a3c += (float)h0[3] * a0;
            a0c += (float)h1[0] * a1; a1c += (float)h1[1] * a1;
            a2c += (float)h1[2] * a1; a3c += (float)h1[3] * a1;
            a0c += (float)h2[0] * a2; a1c += (float)h2[1] * a2;
            a2c += (float)h2[2] * a2; a3c += (float)h2[3] * a2;
            a0c += (float)h3[0] * a3; a1c += (float)h3[1] * a3;
            a2c += (float)h3[2] * a3; a3c += (float)h3[3] * a3;
            a0c += (float)h4[0] * a4; a1c += (float)h4[1] * a4;
            a2c += (float)h4[2] * a4; a3c += (float)h4[3] * a4;
            a0c += (float)h5[0] * a5; a1c += (float)h5[1] * a5;
            a2c += (float)h5[2] * a5; a3c += (float)h5[3] * a5;
            a0c += (float)h6[0] * a6; a1c += (float)h6[1] * a6;
            a2c += (float)h6[2] * a6; a3c += (float)h6[3] * a6;
            a0c += (float)h7[0] * a7; a1c += (float)h7[1] * a7;
            a2c += (float)h7[2] * a7; a3c += (float)h7[3] * a7;
            sw += ((a0 + a1) + (a2 + a3)) + ((a4 + a5) + (a6 + a7));
            k += 8;
            if (k >= mr) break;
            e0 = f0; e1 = f1; e2 = f2; e3 = f3;
        }
    }

    if (valid) {
        const float4 bj = *(const float4*)(bias + j);
        const float4 pj = *(const float4*)(prelu_w + j);
        float inv = 1.f / (sw + 1e-16f);
        float o0 = a0c * inv + bj.x;
        float o1 = a1c * inv + bj.y;
        float o2 = a2c * inv + bj.z;
        float o3 = a3c * inv + bj.w;
        float4 r;
        r.x = (o0 >= 0.f) ? o0 : pj.x * o0;
        r.y = (o1 >= 0.f) ? o1 : pj.y * o1;
        r.z = (o2 >= 0.f) ? o2 : pj.z * o2;
        r.w = (o3 >= 0.f) ? o3 : pj.w * o3;
        *(float4*)(out + (size_t)node * 128 + j) = r;
    }
}

extern "C" void kernel_launch(void* const* d_in, const int* in_sizes, int n_in,
                              void* d_out, int out_size, void* d_ws, size_t ws_size,
                              hipStream_t stream) {
    const float* x      = (const float*)d_in[0];
    const float* Wsrc   = (const float*)d_in[1];
    const float* Wdst   = (const float*)d_in[2];
    const float* att_s  = (const float*)d_in[3];
    const float* att_d  = (const float*)d_in[4];
    const float* bias   = (const float*)d_in[5];
    const float* prelu  = (const float*)d_in[6];
    const int*   ei     = (const int*)d_in[7];
    float* out = (float*)d_out;

    char* ws = (char*)d_ws;
    float*  a_all  = (float*)(ws + OFF_A);
    int*    cnt    = (int*)(ws + OFF_CNT);
    __half* xs     = (__half*)(ws + OFF_XS);
    int2*   bkt    = (int2*)(ws + OFF_BKT);
    __half* swz    = (__half*)(ws + OFF_SWZ);

    char* outb = (char*)d_out;               // scratch; k6_pass overwrites all of it
    u64* coarse  = (u64*)(outb + DOUT_COARSE);
    int* cellcnt = (int*)(outb + DOUT_CELL);

    k0_prep<<<9, 256, 0, stream>>>(Wsrc, Wdst, att_s, att_d, swz);
    k1_gemm<<<(N_NODES + 63) / 64, 256, 0, stream>>>(x, swz, xs, a_all);
    kB_bin<<<NBLK, 256, 0, stream>>>(ei, a_all, coarse, cellcnt);
    kD_fine<<<NB * 2, 512, 0, stream>>>(coarse, cellcnt, cnt, bkt);
    // 4 passes x ceil(N/32) groups; pass = blockIdx&3 for XCD-pinned col slices
    k6_pass<<<4 * ((N_NODES + 31) / 32), 256, 0, stream>>>(bkt, cnt, xs, bias, prelu, out);
}

// Round 9
// 163.883 us; speedup vs baseline: 1.0312x; 1.0312x over previous
//
#include <hip/hip_runtime.h>
#include <hip/hip_fp16.h>

// GAT (2 heads x 64) + PReLU, N=50000, E=800000, feat 128.
// R19: revert R18's kB/kD scale-out (coarse bytes grew, net +4us) back to the
// proven R17 geometry, and halve k6's index-stream instead:
//  - bkt split into per-head arrays bkt0/bkt1, 4 B/edge packed
//    {u16 src | half w << 16} (same 22.4 MB total footprint). Each k6 pass
//    reads only its head's array: 2 int4 idx loads per 8-edge batch (was 4),
//    per-pass bkt traffic halved. Weight decode folds to SDWA WORD_1.
//  - kD writes 2x4B scattered stores (same unique-line RFO bytes).
//  - k6 otherwise identical to R17 (8 nodes x 8 lanes x half4, slice-major
//    xs, pass->XCD pinning). k0/k1/kB identical to R17.

#define N_NODES 50000
#define N_EDGES 800000
#define CAP     56        // max in-degree; deg ~ Poisson(16), P(>56) ~ 1e-9
#define BSH     8         // bucket shift: 256 nodes per bucket
#define NB      196       // ceil(N / 256) buckets
#define CHUNK   4096      // edges per kB block
#define NBLK    196       // ceil(E / CHUNK)
#define CCAP    64        // slots per (bucket,chunk) cell; mean 20.9, 9.4 sigma

// d_ws layout (bytes); total 36,237,120 (R10 proven footprint)
#define OFF_A      0          // a_all: N*4 floats          =   800000
#define OFF_CNT    800000     // cnt:   N ints              =   200000
#define OFF_XS     1000256    // xs:    4*N*32 halves       = 12800000
#define OFF_BKT0   13800256   // bkt0:  N*CAP int           = 11200000
#define OFF_BKT1   25000256   // bkt1:  N*CAP int           = 11200000 (ends 36,200,256)
#define OFF_SWZ    36200256   // swizzled B: 2304 * 16 B    =    36864
// d_out scratch (dead before k6_pass overwrites all 25.6 MB):
#define DOUT_COARSE 0         // NB*NBLK*CCAP*8 = 196*196*64*8 = 19,668,992
#define DOUT_CELL   19668992  // cellcnt = NB*NBLK*4 = 153,664 B
                              // total 19,822,656 < 25,600,000 (d_out)

typedef _Float16 f16x8 __attribute__((ext_vector_type(8)));
typedef _Float16 f16x4 __attribute__((ext_vector_type(4)));
typedef float    f32x4 __attribute__((ext_vector_type(4)));
typedef int      i32x4 __attribute__((ext_vector_type(4)));
typedef unsigned long long u64;

// ---------------------------------------------------------------------------
// k0_prep: build B-fragment buffer for GEMM x @ [W_src | V].
__global__ __launch_bounds__(256) void k0_prep(
    const float* __restrict__ Wsrc, const float* __restrict__ Wdst,
    const float* __restrict__ att_s, const float* __restrict__ att_d,
    __half* __restrict__ swz)
{
    __shared__ float vS[128 * 4];
    const int nt = blockIdx.x;
    const int t = threadIdx.x;
    if (nt == 8) {
        if (t < 128) {
            const float* wsp = Wsrc + t * 128;
            const float* wdp = Wdst + t * 128;
            float a0 = 0.f, a1 = 0.f, a2 = 0.f, a3 = 0.f;
#pragma unroll 8
            for (int c = 0; c < 64; ++c) {
                a0 += wsp[c]      * att_s[c];
                a1 += wsp[64 + c] * att_s[64 + c];
                a2 += wdp[c]      * att_d[c];
                a3 += wdp[64 + c] * att_d[64 + c];
            }
            *(float4*)(vS + t * 4) = make_float4(a0, a1, a2, a3);
        }
        __syncthreads();
    }
    const int kb = t >> 6, L = t & 63;
    const int col = L & 15;
    const int krow = kb * 32 + ((L >> 4) & 3) * 8;
    f16x8 v;
    if (nt < 8) {
#pragma unroll
        for (int j = 0; j < 8; ++j)
            v[j] = (_Float16)Wsrc[(size_t)(krow + j) * 128 + nt * 16 + col];
    } else {
#pragma unroll
        for (int j = 0; j < 8; ++j)
            v[j] = (col < 4) ? (_Float16)vS[(krow + j) * 4 + col] : (_Float16)0.f;
    }
    *(f16x8*)(swz + ((size_t)(kb * 9 + nt) * 64 + L) * 8) = v;
}

// ---------------------------------------------------------------------------
// k1: MFMA GEMM x @ [W_src | V]. Block = 4 waves; wave: 16 rows x 144 cols, K=128.
// Epilogue writes xs in slice-major layout [4][N][32].
__global__ __launch_bounds__(256) void k1_gemm(
    const float* __restrict__ x, const __half* __restrict__ swz,
    __half* __restrict__ xs, float* __restrict__ a_all)
{
    __shared__ __half tile[64 * 136];   // row stride 272B (16B-mult); 17.4 KB
    const int t = threadIdx.x;
    const int w = t >> 6, L = t & 63;
    const int m = L & 15, q = L >> 4;
    const int n_a = blockIdx.x * 64 + w * 16 + m;
    const int rrow = (n_a < N_NODES) ? n_a : (N_NODES - 1);
    const float* xrow = x + (size_t)rrow * 128;

    f32x4 acc[9];
#pragma unroll
    for (int nt = 0; nt < 9; ++nt) acc[nt] = (f32x4){0.f, 0.f, 0.f, 0.f};

#pragma unroll
    for (int kb = 0; kb < 4; ++kb) {
        const int k0 = kb * 32 + q * 8;
        float4 xa = *(const float4*)(xrow + k0);
        float4 xb = *(const float4*)(xrow + k0 + 4);
        f16x8 a;
        a[0] = (_Float16)xa.x; a[1] = (_Float16)xa.y;
        a[2] = (_Float16)xa.z; a[3] = (_Float16)xa.w;
        a[4] = (_Float16)xb.x; a[5] = (_Float16)xb.y;
        a[6] = (_Float16)xb.z; a[7] = (_Float16)xb.w;
        const f16x8* bbase = (const f16x8*)swz + (size_t)(kb * 9) * 64 + L;
#pragma unroll
        for (int nt = 0; nt < 9; ++nt) {
            f16x8 b = bbase[(size_t)nt * 64];
            acc[nt] = __builtin_amdgcn_mfma_f32_16x16x32_f16(a, b, acc[nt], 0, 0, 0);
        }
    }

    // xs epilogue: C/D layout col = lane&15, row = (lane>>4)*4 + reg
    const int rloc = w * 16 + q * 4;              // row-in-tile base for this lane
#pragma unroll
    for (int nt = 0; nt < 8; ++nt) {
#pragma unroll
        for (int r = 0; r < 4; ++r)
            tile[(rloc + r) * 136 + nt * 16 + m] = (__half)acc[nt][r];
    }
    __syncthreads();
    const int n0 = blockIdx.x * 64;
#pragma unroll
    for (int cc = 0; cc < 4; ++cc) {
        int task = cc * 256 + t;                  // 1024 tasks = 64 rows x 16 chunks
        int row = task >> 4, ch = task & 15;      // chunk = 8 halves (cols ch*8..+7)
        int n = n0 + row;
        if (n < N_NODES) {
            ulonglong2 v = *(const ulonglong2*)(tile + row * 136 + ch * 8);
            // slice-major: slice p = ch>>2, in-slice offset (ch&3)*8 halves
            *(ulonglong2*)(xs + ((size_t)(ch >> 2) * N_NODES + n) * 32 + (ch & 3) * 8) = v;
        }
    }

    // a_all from tile 8 (fp32, 4 cols)
    if (m < 4) {
#pragma unroll
        for (int r = 0; r < 4; ++r) {
            int n = n0 + rloc + r;
            if (n < N_NODES) a_all[(size_t)n * 4 + m] = acc[8][r];
        }
    }
}

// ---------------------------------------------------------------------------
// kB: per-chunk scatter into this chunk's private cells. (Identical to R17.)
__global__ __launch_bounds__(256) void kB_bin(
    const int* __restrict__ ei, const float* __restrict__ a_all,
    u64* __restrict__ coarse, int* __restrict__ cellcnt)
{
    __shared__ int lcnt[NB];
    const int t = threadIdx.x;
    if (t < NB) lcnt[t] = 0;
    __syncthreads();
    const int e0 = blockIdx.x * CHUNK;
#pragma unroll
    for (int u = 0; u < 8; ++u) {
        int e = e0 + u * 512 + t * 2;             // even; E even -> e+1 valid too
        if (e < N_EDGES) {
            int2 ss = *(const int2*)(ei + e);
            int2 dd = *(const int2*)(ei + N_EDGES + e);
            float2 as0 = *(const float2*)(a_all + (size_t)ss.x * 4);
            float2 ad0 = *(const float2*)(a_all + (size_t)dd.x * 4 + 2);
            float2 as1 = *(const float2*)(a_all + (size_t)ss.y * 4);
            float2 ad1 = *(const float2*)(a_all + (size_t)dd.y * 4 + 2);
            float e00 = as0.x + ad0.x, e01 = as0.y + ad0.y;
            float e10 = as1.x + ad1.x, e11 = as1.y + ad1.y;
            e00 = (e00 >= 0.f) ? e00 : 0.2f * e00;
            e01 = (e01 >= 0.f) ? e01 : 0.2f * e01;
            e10 = (e10 >= 0.f) ? e10 : 0.2f * e10;
            e11 = (e11 >= 0.f) ? e11 : 0.2f * e11;
            // no max-shift: |e| small -> exp safe in fp32, math identical
            __half2 hw0 = __floats2half2_rn(__expf(e00), __expf(e01));
            __half2 hw1 = __floats2half2_rn(__expf(e10), __expf(e11));
            unsigned lo0 = (unsigned)ss.x | ((unsigned)(dd.x & 255) << 16);
            unsigned lo1 = (unsigned)ss.y | ((unsigned)(dd.y & 255) << 16);
            u64 ent0 = (u64)lo0 | ((u64)*reinterpret_cast<unsigned*>(&hw0) << 32);
            u64 ent1 = (u64)lo1 | ((u64)*reinterpret_cast<unsigned*>(&hw1) << 32);
            int b0 = dd.x >> BSH, b1 = dd.y >> BSH;
            int p0 = atomicAdd(&lcnt[b0], 1);
            int p1 = atomicAdd(&lcnt[b1], 1);
            if (p0 < CCAP)
                coarse[((size_t)b0 * NBLK + blockIdx.x) * CCAP + p0] = ent0;
            if (p1 < CCAP)
                coarse[((size_t)b1 * NBLK + blockIdx.x) * CCAP + p1] = ent1;
        }
    }
    __syncthreads();
    if (t < NB) {
        int c = lcnt[t];
        cellcnt[t * NBLK + blockIdx.x] = (c < CCAP) ? c : CCAP;
    }
}

// ---------------------------------------------------------------------------
// kD: one 512-thread block per 256-node bucket (R17 geometry); per-dst
// cursors in LDS; gap-skipping slot-pair reads; writes SPLIT per-head packed
// entries {u16 src | half w << 16} to bkt0/bkt1; zero-pads rows to x8.
__global__ __launch_bounds__(512) void kD_fine(
    const u64* __restrict__ coarse, const int* __restrict__ cellcnt,
    int* __restrict__ cnt, int* __restrict__ bkt0, int* __restrict__ bkt1)
{
    __shared__ int cur[256];
    __shared__ int ccnt[NBLK];
    const int b = blockIdx.x, t = threadIdx.x;
    if (t < 256) cur[t] = 0;
    if (t < NBLK) ccnt[t] = cellcnt[b * NBLK + t];
    __syncthreads();
    const u64* src = coarse + (size_t)b * NBLK * CCAP;
    const int HALF = CCAP / 2;                       // 32 pairs per cell (pow2)
    for (int g2 = t; g2 < NBLK * HALF; g2 += 512) {
        int c = g2 >> 5, sp = (g2 & 31) * 2;
        int cc = ccnt[c];
        if (sp < cc) {
            ulonglong2 pr = *(const ulonglong2*)(src + (size_t)c * CCAP + sp);
            {
                unsigned lo = (unsigned)pr.x;
                unsigned hw = (unsigned)(pr.x >> 32);   // half2(w0, w1)
                int drel = (lo >> 16) & 255;
                int pos = atomicAdd(&cur[drel], 1);
                if (pos < CAP) {
                    int idx = ((b << BSH) + drel) * CAP + pos;
                    bkt0[idx] = (int)((lo & 0xFFFF) | (hw << 16));
                    bkt1[idx] = (int)((lo & 0xFFFF) | (hw & 0xFFFF0000u));
                }
            }
            if (sp + 1 < cc) {
                unsigned lo = (unsigned)pr.y;
                unsigned hw = (unsigned)(pr.y >> 32);
                int drel = (lo >> 16) & 255;
                int pos = atomicAdd(&cur[drel], 1);
                if (pos < CAP) {
                    int idx = ((b << BSH) + drel) * CAP + pos;
                    bkt0[idx] = (int)((lo & 0xFFFF) | (hw << 16));
                    bkt1[idx] = (int)((lo & 0xFFFF) | (hw & 0xFFFF0000u));
                }
            }
        }
    }
    __syncthreads();
    if (t < 256) {
        int d = (b << BSH) + t;
        if (d < N_NODES) {
            int c = cur[t];
            cnt[d] = c;
            int cc = (c < CAP) ? c : CAP;
            int ce = (cc + 7) & ~7;                // pad to multiple of 8
            for (int p = cc; p < ce; ++p) {
                bkt0[d * CAP + p] = 0;
                bkt1[d * CAP + p] = 0;
            }
        }
    }
}

// ---------------------------------------------------------------------------
// k6_pass: column-pass aggregation over slice-major xs; pass = blockIdx&3
// (HW round-robin -> XCD x sees pass x&3 only; slice 3.2 MB L2-resident).
// Wave = 8 nodes x 8 lanes x half4. Per-head packed bkt: 2 int4 idx loads
// per 8-edge batch; weight decode via >>16 (SDWA WORD_1 in the cvt).
__global__ __launch_bounds__(256) void k6_pass(
    const int* __restrict__ bkt0, const int* __restrict__ bkt1,
    const int* __restrict__ cnt, const __half* __restrict__ xs,
    const float* __restrict__ bias, const float* __restrict__ prelu_w,
    float* __restrict__ out)
{
    const int pass = blockIdx.x & 3;            // XCD (blockIdx%8) sees pass x&3 only
    const int grp  = blockIdx.x >> 2;           // 32 nodes per block
    const int t = threadIdx.x;
    const int w = t >> 6, lane = t & 63;
    const int l8 = lane & 7;                    // lane-in-node-group
    const int node = grp * 32 + w * 8 + (lane >> 3);
    const int c4 = l8 * 4;                      // in-slice column (4 cols/lane)
    const int j = pass * 32 + c4;               // global output column
    const __half* xsp = xs + pass * (N_NODES * 32);   // 32-bit offset (6.4M)
    const int* bk = (pass & 2) ? bkt1 : bkt0;   // head = col>=64

    const bool valid = (node < N_NODES);
    int m = 0;
    if (valid) { m = cnt[node]; if (m > CAP) m = CAP; }
    const int mr = (m + 7) & ~7;                // padded-valid region
    const i32x4* row = (const i32x4*)(bk + (valid ? node : 0) * CAP);

    float a0c = 0.f, a1c = 0.f, a2c = 0.f, a3c = 0.f, sw = 0.f;
    if (mr) {
        i32x4 e0 = row[0], e1 = row[1];
        int k = 0;
        for (;;) {
            const bool more = (k + 8 < mr);
            i32x4 f0, f1;
            if (more) {
                const i32x4* nr = row + ((k + 8) >> 2);
                f0 = nr[0]; f1 = nr[1];
            }
            // 8 xs loads (half4 = 8B each; 8 lanes cover the 64B slice row)
            f16x4 h0 = *(const f16x4*)(xsp + (e0[0] & 0xFFFF) * 32 + c4);
            f16x4 h1 = *(const f16x4*)(xsp + (e0[1] & 0xFFFF) * 32 + c4);
            f16x4 h2 = *(const f16x4*)(xsp + (e0[2] & 0xFFFF) * 32 + c4);
            f16x4 h3 = *(const f16x4*)(xsp + (e0[3] & 0xFFFF) * 32 + c4);
            f16x4 h4 = *(const f16x4*)(xsp + (e1[0] & 0xFFFF) * 32 + c4);
            f16x4 h5 = *(const f16x4*)(xsp + (e1[1] & 0xFFFF) * 32 + c4);
            f16x4 h6 = *(const f16x4*)(xsp + (e1[2] & 0xFFFF) * 32 + c4);
            f16x4 h7 = *(const f16x4*)(xsp + (e1[3] & 0xFFFF) * 32 + c4);
            float a0 = __half2float(__ushort_as_half((unsigned short)(((unsigned)e0[0]) >> 16)));
            float a1 = __half2float(__ushort_as_half((unsigned short)(((unsigned)e0[1]) >> 16)));
            float a2 = __half2float(__ushort_as_half((unsigned short)(((unsigned)e0[2]) >> 16)));
            float a3 = __half2float(__ushort_as_half((unsigned short)(((unsigned)e0[3]) >> 16)));
            float a4 = __half2float(__ushort_as_half((unsigned short)(((unsigned)e1[0]) >> 16)));
            float a5 = __half2float(__ushort_as_half((unsigned short)(((unsigned)e1[1]) >> 16)));
            float a6 = __half2float(__ushort_as_half((unsigned short)(((unsigned)e1[2]) >> 16)));
            float a7 = __half2float(__ushort_as_half((unsigned short)(((unsigned)e1[3]) >> 16)));
            a0c += (float)h0[0] * a0; a1c += (float)h0[1] * a0;
            a2c += (float)h0[2] * a0; a3c += (float)h0[3] * a0;
            a0c += (float)h1[0] * a1; a1c += (float)h1[1] * a1;
            a2c += (float)h1[2] * a1; a3c += (float)h1[3] * a1;
            a0c += (float)h2[0] * a2; a1c += (float)h2[1] * a2;
            a2c += (float)h2[2] * a2; a3c += (float)h2[3] * a2;
            a0c += (float)h3[0] * a3; a1c += (float)h3[1] * a3;
            a2c += (float)h3[2] * a3; a3c += (float)h3[3] * a3;
            a0c += (float)h4[0] * a4; a1c += (float)h4[1] * a4;
            a2c += (float)h4[2] * a4; a3c += (float)h4[3] * a4;
            a0c += (float)h5[0] * a5; a1c += (float)h5[1] * a5;
            a2c += (float)h5[2] * a5; a3c += (float)h5[3] * a5;
            a0c += (float)h6[0] * a6; a1c += (float)h6[1] * a6;
            a2c += (float)h6[2] * a6; a3c += (float)h6[3] * a6;
            a0c += (float)h7[0] * a7; a1c += (float)h7[1] * a7;
            a2c += (float)h7[2] * a7; a3c += (float)h7[3] * a7;
            sw += ((a0 + a1) + (a2 + a3)) + ((a4 + a5) + (a6 + a7));
            k += 8;
            if (k >= mr) break;
            e0 = f0; e1 = f1;
        }
    }

    if (valid) {
        const float4 bj = *(const float4*)(bias + j);
        const float4 pj = *(const float4*)(prelu_w + j);
        float inv = 1.f / (sw + 1e-16f);
        float o0 = a0c * inv + bj.x;
        float o1 = a1c * inv + bj.y;
        float o2 = a2c * inv + bj.z;
        float o3 = a3c * inv + bj.w;
        float4 r;
        r.x = (o0 >= 0.f) ? o0 : pj.x * o0;
        r.y = (o1 >= 0.f) ? o1 : pj.y * o1;
        r.z = (o2 >= 0.f) ? o2 : pj.z * o2;
        r.w = (o3 >= 0.f) ? o3 : pj.w * o3;
        *(float4*)(out + (size_t)node * 128 + j) = r;
    }
}

extern "C" void kernel_launch(void* const* d_in, const int* in_sizes, int n_in,
                              void* d_out, int out_size, void* d_ws, size_t ws_size,
                              hipStream_t stream) {
    const float* x      = (const float*)d_in[0];
    const float* Wsrc   = (const float*)d_in[1];
    const float* Wdst   = (const float*)d_in[2];
    const float* att_s  = (const float*)d_in[3];
    const float* att_d  = (const float*)d_in[4];
    const float* bias   = (const float*)d_in[5];
    const float* prelu  = (const float*)d_in[6];
    const int*   ei     = (const int*)d_in[7];
    float* out = (float*)d_out;

    char* ws = (char*)d_ws;
    float*  a_all  = (float*)(ws + OFF_A);
    int*    cnt    = (int*)(ws + OFF_CNT);
    __half* xs     = (__half*)(ws + OFF_XS);
    int*    bkt0   = (int*)(ws + OFF_BKT0);
    int*    bkt1   = (int*)(ws + OFF_BKT1);
    __half* swz    = (__half*)(ws + OFF_SWZ);

    char* outb = (char*)d_out;               // scratch; k6_pass overwrites all of it
    u64* coarse  = (u64*)(outb + DOUT_COARSE);
    int* cellcnt = (int*)(outb + DOUT_CELL);

    k0_prep<<<9, 256, 0, stream>>>(Wsrc, Wdst, att_s, att_d, swz);
    k1_gemm<<<(N_NODES + 63) / 64, 256, 0, stream>>>(x, swz, xs, a_all);
    kB_bin<<<NBLK, 256, 0, stream>>>(ei, a_all, coarse, cellcnt);
    kD_fine<<<NB, 512, 0, stream>>>(coarse, cellcnt, cnt, bkt0, bkt1);
    // 4 passes x ceil(N/32) groups; pass = blockIdx&3 for XCD-pinned col slices
    k6_pass<<<4 * ((N_NODES + 31) / 32), 256, 0, stream>>>(bkt0, bkt1, cnt, xs, bias, prelu, out);
}